// Round 1
// baseline (1392.355 us; speedup 1.0000x reference)
//
#include <hip/hip_runtime.h>
#include <hip/hip_bf16.h>

// ---------------------------------------------------------------------------
// DeepseekV2 MoE forward, sparse grouped-GEMM formulation.
// Pipeline: cvt_x -> router(fp32) -> build_map -> gemm<0> routed gate_up ->
//           silu(routed, weight folded) -> gemm<1> shared gate_up ->
//           silu(shared) -> gemm<3> shared down (stores d_out) ->
//           gemm<2> routed down (atomicAdd into d_out)
// ---------------------------------------------------------------------------

typedef __bf16 bf16_t;
typedef __attribute__((ext_vector_type(8))) __bf16 bf16x8;
typedef __attribute__((ext_vector_type(4))) float f32x4;

#define T_TOK 1024
#define HDIM  2048
#define IDIM  1408
#define NEXP  16
#define ISH   2816
#define TOPK  4
#define MAXSLOTS 6144   // 4096 assignments + 16 * 128 padding, rounded up
#define MAXTILES 48

#define BM 128
#define BN 128
#define BK 32
#define LDSS 40         // BK + 8 bf16 pad: keeps 16B alignment, spreads banks

// ---------------------------------------------------------------------------
// fp32 -> bf16 conversion of hidden_states (read once, reused by 2 GEMMs)
// ---------------------------------------------------------------------------
__global__ void cvt_x_kernel(const float* __restrict__ x, bf16_t* __restrict__ xb)
{
    const size_t i = ((size_t)blockIdx.x * blockDim.x + threadIdx.x) * 8;
    float4 a = *(const float4*)(x + i);
    float4 b = *(const float4*)(x + i + 4);
    bf16x8 v;
    v[0] = (bf16_t)a.x; v[1] = (bf16_t)a.y; v[2] = (bf16_t)a.z; v[3] = (bf16_t)a.w;
    v[4] = (bf16_t)b.x; v[5] = (bf16_t)b.y; v[6] = (bf16_t)b.z; v[7] = (bf16_t)b.w;
    *(bf16x8*)(xb + i) = v;
}

// ---------------------------------------------------------------------------
// Router: fp32 logits + sigmoid + grouped top-k. One wave per token.
// Selection must be bit-faithful to the fp32 reference (a flipped expert pick
// is an O(1) output error), so everything here stays fp32.
// ---------------------------------------------------------------------------
__global__ __launch_bounds__(64)
void router_kernel(const float* __restrict__ x, const float* __restrict__ gate_w,
                   const float* __restrict__ bias,
                   int* __restrict__ topk_ids, float* __restrict__ topk_w)
{
    const int t = blockIdx.x;
    const int lane = threadIdx.x;
    const float* xr = x + (size_t)t * HDIM;
    float xv[32];
#pragma unroll
    for (int i = 0; i < 32; i++) xv[i] = xr[lane + i * 64];

    float lg[NEXP];
#pragma unroll
    for (int e = 0; e < NEXP; e++) {
        const float* wr = gate_w + (size_t)e * HDIM;
        float p = 0.f;
#pragma unroll
        for (int i = 0; i < 32; i++) p = fmaf(xv[i], wr[lane + i * 64], p);
#pragma unroll
        for (int off = 32; off > 0; off >>= 1) p += __shfl_xor(p, off);
        lg[e] = p;  // full sum in every lane (butterfly)
    }

    if (lane == 0) {
        float sc[NEXP], sb[NEXP];
#pragma unroll
        for (int e = 0; e < NEXP; e++) {
            sc[e] = 1.f / (1.f + expf(-lg[e]));
            sb[e] = sc[e] + bias[e];
        }
        // group score = sum of top-2 biased scores within each group of 4
        float gsc[4];
#pragma unroll
        for (int g = 0; g < 4; g++) {
            float m1 = -1e30f, m2 = -1e30f;
#pragma unroll
            for (int j = 0; j < 4; j++) {
                float v = sb[g * 4 + j];
                if (v > m1) { m2 = m1; m1 = v; }
                else if (v > m2) m2 = v;
            }
            gsc[g] = m1 + m2;
        }
        // top-2 groups (strict > keeps lowest index on ties, like lax.top_k)
        int gA = 0;
        for (int g = 1; g < 4; g++) if (gsc[g] > gsc[gA]) gA = g;
        int gB = (gA == 0) ? 1 : 0;
        for (int g = 0; g < 4; g++) if (g != gA && gsc[g] > gsc[gB]) gB = g;
        bool gm[4] = {false, false, false, false};
        gm[gA] = true; gm[gB] = true;
        // top-4 experts among unmasked biased scores
        int ids[TOPK]; bool taken[NEXP] = {false};
        for (int k = 0; k < TOPK; k++) {
            float best = -1e30f; int bi = 0;
            for (int e = 0; e < NEXP; e++)
                if (gm[e >> 2] && !taken[e] && sb[e] > best) { best = sb[e]; bi = e; }
            taken[bi] = true; ids[k] = bi;
        }
        // weights from UNbiased scores, renormalized; fold in routed_scaling 2.5
        float s = 0.f;
        for (int k = 0; k < TOPK; k++) s += sc[ids[k]];
        float inv = 2.5f / s;
        for (int k = 0; k < TOPK; k++) {
            topk_ids[t * TOPK + k] = ids[k];
            topk_w[t * TOPK + k]   = sc[ids[k]] * inv;
        }
    }
}

// ---------------------------------------------------------------------------
// Counting sort into 128-aligned per-expert segments + tile table.
// Single block; E=16 threads do the scan work (4096 assignments).
// ---------------------------------------------------------------------------
__global__ __launch_bounds__(64)
void build_map_kernel(const int* __restrict__ topk_ids, const float* __restrict__ topk_w,
                      int* __restrict__ map_token, float* __restrict__ map_w,
                      int4* __restrict__ tile_info)
{
    const int tid = threadIdx.x;
    __shared__ int cnt[NEXP], seg[NEXP];

    // zero the whole map (padded slots must have weight 0)
    for (int i = tid; i < MAXSLOTS; i += 64) { map_token[i] = 0; map_w[i] = 0.f; }

    if (tid < NEXP) {
        int c = 0;
        for (int s = 0; s < T_TOK * TOPK; s++) c += (topk_ids[s] == tid);
        cnt[tid] = c;
    }
    __syncthreads();

    if (tid == 0) {
        int off = 0, tt = 0;
        for (int e = 0; e < NEXP; e++) {
            seg[e] = off;
            int tiles = (cnt[e] + BM - 1) / BM;
            for (int i = 0; i < tiles; i++) {
                int rem = cnt[e] - i * BM;
                tile_info[tt++] = make_int4(e, off + i * BM, rem < BM ? rem : BM, 0);
            }
            off += tiles * BM;
        }
        for (; tt < MAXTILES; tt++) tile_info[tt] = make_int4(-1, 0, 0, 0);
    }
    __syncthreads();

    if (tid < NEXP) {
        int o = seg[tid];
        for (int s = 0; s < T_TOK * TOPK; s++) {
            if (topk_ids[s] == tid) {
                map_token[o] = s >> 2;        // token id
                map_w[o]     = topk_w[s];
                o++;
            }
        }
    }
}

// ---------------------------------------------------------------------------
// SiLU(g)*u (* per-slot combine weight for the routed path).
// gu rows are [g | u] of width 2*I; grid covers rows*I/8 exactly.
// ---------------------------------------------------------------------------
__global__ void silu_kernel(const bf16_t* __restrict__ gu, bf16_t* __restrict__ act,
                            const float* __restrict__ w, int I)
{
    const unsigned idx = ((unsigned)blockIdx.x * blockDim.x + threadIdx.x) * 8u;
    const unsigned r = idx / (unsigned)I;
    const unsigned c = idx % (unsigned)I;
    const bf16x8 g = *(const bf16x8*)(gu + (size_t)r * 2 * I + c);
    const bf16x8 u = *(const bf16x8*)(gu + (size_t)r * 2 * I + I + c);
    const float wt = w ? w[r] : 1.0f;
    bf16x8 o;
#pragma unroll
    for (int j = 0; j < 8; j++) {
        float gf = (float)g[j], uf = (float)u[j];
        float a = gf / (1.f + expf(-gf)) * uf * wt;
        o[j] = (bf16_t)a;
    }
    *(bf16x8*)(act + (size_t)r * I + c) = o;
}

// ---------------------------------------------------------------------------
// Tiled bf16 MFMA GEMM, 128x128x32, 256 threads (4 waves, 2x2 of 64x64).
// A: bf16 [rows x lda] (optionally gathered rows via map_token).
// B: fp32 [K x N] row-major, converted to bf16 during LDS staging
//    (stored transposed [n][k] so fragments are contiguous 16B ds_read_b128).
// MODE 0: routed gate_up  (A rows = x[map_token[slot]],    C -> bf16 gu[slot])
// MODE 1: shared gate_up  (A rows = x[row],                C -> bf16 gu[row])
// MODE 2: routed down     (A rows = act[slot],  C -> atomicAdd f32 out[token])
// MODE 3: shared down     (A rows = act_s[row], C -> store f32 out[row])
// ---------------------------------------------------------------------------
template<int MODE>
__global__ __launch_bounds__(256, 2)
void gemm_kernel(const bf16_t* __restrict__ A, int lda,
                 const float* __restrict__ B, size_t bstride,
                 int K, int N,
                 const int4* __restrict__ tile_info,
                 const int* __restrict__ map_token,
                 bf16_t* __restrict__ Cb, float* __restrict__ Cf)
{
    const int tid = threadIdx.x;
    int row0, nvalid;
    const float* Bex;
    if (MODE == 0 || MODE == 2) {
        int4 ti = tile_info[blockIdx.y];
        if (ti.x < 0) return;                 // unused padded tile
        Bex = B + (size_t)ti.x * bstride;
        row0 = ti.y;
        nvalid = ti.z;
    } else {
        Bex = B;
        row0 = blockIdx.y * BM;
        nvalid = BM;
    }
    const int n0 = blockIdx.x * BN;

    __shared__ __align__(16) bf16_t As[BM * LDSS];
    __shared__ __align__(16) bf16_t Bs[BN * LDSS];

    // A staging: 512 chunks of 8 bf16 (16B); thread does rows r0 and r0+64
    const int r0 = tid >> 2;
    const int r1 = r0 + 64;
    const int kq = (tid & 3) * 8;
    const bool v0 = r0 < nvalid, v1 = r1 < nvalid;
    size_t arow0, arow1;
    if (MODE == 0) {
        arow0 = v0 ? (size_t)map_token[row0 + r0] : 0;
        arow1 = v1 ? (size_t)map_token[row0 + r1] : 0;
    } else {
        arow0 = (size_t)(row0 + r0);
        arow1 = (size_t)(row0 + r1);
    }
    // B staging: thread covers 16 k's at one n (k-strided coalesced dword loads)
    const int bn = tid & 127;
    const int bk = (tid >> 7) * 16;

    const int lane = tid & 63;
    const int wv = tid >> 6;
    const int wrow = (wv >> 1) * 64;
    const int wcol = (wv & 1) * 64;
    const int lr = lane & 15;
    const int lk = (lane >> 4) * 8;

    f32x4 acc[4][4];
    const f32x4 zero = {0.f, 0.f, 0.f, 0.f};
#pragma unroll
    for (int i = 0; i < 4; i++)
#pragma unroll
        for (int j = 0; j < 4; j++) acc[i][j] = zero;

    for (int k0 = 0; k0 < K; k0 += BK) {
        // ---- stage A (zero-fill rows past nvalid -> padded gu rows are 0) ----
        int4 a0 = make_int4(0, 0, 0, 0), a1 = make_int4(0, 0, 0, 0);
        if (v0) a0 = *(const int4*)(A + arow0 * lda + k0 + kq);
        if (v1) a1 = *(const int4*)(A + arow1 * lda + k0 + kq);
        *(int4*)(&As[r0 * LDSS + kq]) = a0;
        *(int4*)(&As[r1 * LDSS + kq]) = a1;
        // ---- stage B: fp32 -> bf16, transposed to [n][k] ----
        const float* bp = Bex + (size_t)(k0 + bk) * N + (n0 + bn);
        float bv[16];
#pragma unroll
        for (int i = 0; i < 16; i++) bv[i] = bp[(size_t)i * N];
        bf16x8 p0, p1;
#pragma unroll
        for (int i = 0; i < 8; i++) { p0[i] = (bf16_t)bv[i]; p1[i] = (bf16_t)bv[i + 8]; }
        *(bf16x8*)(&Bs[bn * LDSS + bk]) = p0;
        *(bf16x8*)(&Bs[bn * LDSS + bk + 8]) = p1;
        __syncthreads();
        // ---- fragments + MFMA ----
        bf16x8 af[4], bfrag[4];
#pragma unroll
        for (int im = 0; im < 4; im++)
            af[im] = *(const bf16x8*)(&As[(wrow + im * 16 + lr) * LDSS + lk]);
#pragma unroll
        for (int in = 0; in < 4; in++)
            bfrag[in] = *(const bf16x8*)(&Bs[(wcol + in * 16 + lr) * LDSS + lk]);
#pragma unroll
        for (int im = 0; im < 4; im++)
#pragma unroll
            for (int in = 0; in < 4; in++)
                acc[im][in] = __builtin_amdgcn_mfma_f32_16x16x32_bf16(
                    af[im], bfrag[in], acc[im][in], 0, 0, 0);
        __syncthreads();
    }

    // ---- epilogue: C/D layout col = lane&15, row = (lane>>4)*4 + reg ----
#pragma unroll
    for (int im = 0; im < 4; im++) {
#pragma unroll
        for (int j = 0; j < 4; j++) {
            const int rl = wrow + im * 16 + (lane >> 4) * 4 + j;
            if (MODE == 2) {
                if (rl < nvalid) {
                    const size_t orow = (size_t)map_token[row0 + rl] * N;
#pragma unroll
                    for (int in = 0; in < 4; in++) {
                        const int cl = n0 + wcol + in * 16 + (lane & 15);
                        atomicAdd(&Cf[orow + cl], acc[im][in][j]);
                    }
                }
            } else if (MODE == 3) {
                const size_t orow = (size_t)(row0 + rl) * N;
#pragma unroll
                for (int in = 0; in < 4; in++) {
                    const int cl = n0 + wcol + in * 16 + (lane & 15);
                    Cf[orow + cl] = acc[im][in][j];
                }
            } else {
                const size_t orow = (size_t)(row0 + rl) * N;
#pragma unroll
                for (int in = 0; in < 4; in++) {
                    const int cl = n0 + wcol + in * 16 + (lane & 15);
                    Cb[orow + cl] = (bf16_t)acc[im][in][j];
                }
            }
        }
    }
}

// ---------------------------------------------------------------------------
// Workspace layout (needs ~61 MB):
//   0x0000000  x_bf16      1024*2048*2   = 4 MB
//   0x0400000  topk_ids    4096*4
//   0x0404000  topk_w      4096*4
//   0x0408000  map_token   6144*4
//   0x0410000  map_w       6144*4
//   0x0418000  tile_info   48*16
//   0x0500000  act_routed  6144*1408*2   = 16.5 MB
//   0x1600000  act_shared  1024*2816*2   = 5.5 MB
//   0x1C00000  gu          6144*2816*2   = 33 MB   (reused by shared gate_up)
// ---------------------------------------------------------------------------
extern "C" void kernel_launch(void* const* d_in, const int* in_sizes, int n_in,
                              void* d_out, int out_size, void* d_ws, size_t ws_size,
                              hipStream_t stream)
{
    const float* x    = (const float*)d_in[0];
    const float* gw   = (const float*)d_in[1];
    const float* bias = (const float*)d_in[2];
    const float* wgu  = (const float*)d_in[3];
    const float* wdn  = (const float*)d_in[4];
    const float* sgu  = (const float*)d_in[5];
    const float* sdn  = (const float*)d_in[6];
    float* out = (float*)d_out;

    char* ws = (char*)d_ws;
    bf16_t* x_bf  = (bf16_t*)(ws);
    int*    tids  = (int*)  (ws + 0x400000);
    float*  tw    = (float*)(ws + 0x404000);
    int*    mtok  = (int*)  (ws + 0x408000);
    float*  mw    = (float*)(ws + 0x410000);
    int4*   tinfo = (int4*) (ws + 0x418000);
    bf16_t* act_r = (bf16_t*)(ws + 0x500000);
    bf16_t* act_s = (bf16_t*)(ws + 0x1600000);
    bf16_t* gu    = (bf16_t*)(ws + 0x1C00000);

    cvt_x_kernel<<<1024, 256, 0, stream>>>(x, x_bf);                 // 1024*256*8 == T*H
    router_kernel<<<T_TOK, 64, 0, stream>>>(x, gw, bias, tids, tw);
    build_map_kernel<<<1, 64, 0, stream>>>(tids, tw, mtok, mw, tinfo);

    // routed gate_up: [slots x 2816] = gather(x) @ w_gate_up[e]
    gemm_kernel<0><<<dim3(2 * IDIM / BN, MAXTILES), 256, 0, stream>>>(
        x_bf, HDIM, wgu, (size_t)HDIM * 2 * IDIM, HDIM, 2 * IDIM, tinfo, mtok, gu, nullptr);
    // silu + combine weight -> act_r
    silu_kernel<<<MAXSLOTS * IDIM / (8 * 256), 256, 0, stream>>>(gu, act_r, mw, IDIM);

    // shared gate_up (reuses gu buffer)
    gemm_kernel<1><<<dim3(2 * ISH / BN, T_TOK / BM), 256, 0, stream>>>(
        x_bf, HDIM, sgu, 0, HDIM, 2 * ISH, nullptr, nullptr, gu, nullptr);
    silu_kernel<<<T_TOK * ISH / (8 * 256), 256, 0, stream>>>(gu, act_s, nullptr, ISH);

    // shared down: writes every element of d_out (initializes it)
    gemm_kernel<3><<<dim3(HDIM / BN, T_TOK / BM), 256, 0, stream>>>(
        act_s, ISH, sdn, 0, ISH, HDIM, nullptr, nullptr, nullptr, out);
    // routed down: atomicAdd per-token contributions on top
    gemm_kernel<2><<<dim3(HDIM / BN, MAXTILES), 256, 0, stream>>>(
        act_r, IDIM, wdn, (size_t)IDIM * HDIM, IDIM, HDIM, tinfo, mtok, nullptr, out);
}

// Round 2
// 954.285 us; speedup vs baseline: 1.4591x; 1.4591x over previous
//
#include <hip/hip_runtime.h>
#include <hip/hip_bf16.h>

// ---------------------------------------------------------------------------
// DeepseekV2 MoE forward, sparse grouped-GEMM formulation.
// Pipeline: cvt_x -> router(fp32) -> build_map -> gemm<0> routed gate_up ->
//           silu(routed, weight folded) -> gemm<1> shared gate_up ->
//           silu(shared) -> gemm<3> shared down (stores d_out) ->
//           gemm<2> routed down (atomicAdd into d_out)
// R1: build_map parallelized (was 490us serial single-wave -> atomics sort)
// ---------------------------------------------------------------------------

typedef __bf16 bf16_t;
typedef __attribute__((ext_vector_type(8))) __bf16 bf16x8;
typedef __attribute__((ext_vector_type(4))) float f32x4;

#define T_TOK 1024
#define HDIM  2048
#define IDIM  1408
#define NEXP  16
#define ISH   2816
#define TOPK  4
#define MAXSLOTS 6144   // 4096 assignments + 16 * 128 padding, rounded up
#define MAXTILES 48

#define BM 128
#define BN 128
#define BK 32
#define LDSS 40         // BK + 8 bf16 pad: keeps 16B alignment, spreads banks

// ---------------------------------------------------------------------------
// fp32 -> bf16 conversion of hidden_states (read once, reused by 2 GEMMs)
// ---------------------------------------------------------------------------
__global__ void cvt_x_kernel(const float* __restrict__ x, bf16_t* __restrict__ xb)
{
    const size_t i = ((size_t)blockIdx.x * blockDim.x + threadIdx.x) * 8;
    float4 a = *(const float4*)(x + i);
    float4 b = *(const float4*)(x + i + 4);
    bf16x8 v;
    v[0] = (bf16_t)a.x; v[1] = (bf16_t)a.y; v[2] = (bf16_t)a.z; v[3] = (bf16_t)a.w;
    v[4] = (bf16_t)b.x; v[5] = (bf16_t)b.y; v[6] = (bf16_t)b.z; v[7] = (bf16_t)b.w;
    *(bf16x8*)(xb + i) = v;
}

// ---------------------------------------------------------------------------
// Router: fp32 logits + sigmoid + grouped top-k. One wave per token.
// Selection must be bit-faithful to the fp32 reference (a flipped expert pick
// is an O(1) output error), so everything here stays fp32.
// ---------------------------------------------------------------------------
__global__ __launch_bounds__(64)
void router_kernel(const float* __restrict__ x, const float* __restrict__ gate_w,
                   const float* __restrict__ bias,
                   int* __restrict__ topk_ids, float* __restrict__ topk_w)
{
    const int t = blockIdx.x;
    const int lane = threadIdx.x;
    const float* xr = x + (size_t)t * HDIM;
    float xv[32];
#pragma unroll
    for (int i = 0; i < 32; i++) xv[i] = xr[lane + i * 64];

    float lg[NEXP];
#pragma unroll
    for (int e = 0; e < NEXP; e++) {
        const float* wr = gate_w + (size_t)e * HDIM;
        float p = 0.f;
#pragma unroll
        for (int i = 0; i < 32; i++) p = fmaf(xv[i], wr[lane + i * 64], p);
#pragma unroll
        for (int off = 32; off > 0; off >>= 1) p += __shfl_xor(p, off);
        lg[e] = p;  // full sum in every lane (butterfly)
    }

    if (lane == 0) {
        float sc[NEXP], sb[NEXP];
#pragma unroll
        for (int e = 0; e < NEXP; e++) {
            sc[e] = 1.f / (1.f + expf(-lg[e]));
            sb[e] = sc[e] + bias[e];
        }
        // group score = sum of top-2 biased scores within each group of 4
        float gsc[4];
#pragma unroll
        for (int g = 0; g < 4; g++) {
            float m1 = -1e30f, m2 = -1e30f;
#pragma unroll
            for (int j = 0; j < 4; j++) {
                float v = sb[g * 4 + j];
                if (v > m1) { m2 = m1; m1 = v; }
                else if (v > m2) m2 = v;
            }
            gsc[g] = m1 + m2;
        }
        // top-2 groups (strict > keeps lowest index on ties, like lax.top_k)
        int gA = 0;
        for (int g = 1; g < 4; g++) if (gsc[g] > gsc[gA]) gA = g;
        int gB = (gA == 0) ? 1 : 0;
        for (int g = 0; g < 4; g++) if (g != gA && gsc[g] > gsc[gB]) gB = g;
        bool gm[4] = {false, false, false, false};
        gm[gA] = true; gm[gB] = true;
        // top-4 experts among unmasked biased scores
        int ids[TOPK]; bool taken[NEXP] = {false};
        for (int k = 0; k < TOPK; k++) {
            float best = -1e30f; int bi = 0;
            for (int e = 0; e < NEXP; e++)
                if (gm[e >> 2] && !taken[e] && sb[e] > best) { best = sb[e]; bi = e; }
            taken[bi] = true; ids[k] = bi;
        }
        // weights from UNbiased scores, renormalized; fold in routed_scaling 2.5
        float s = 0.f;
        for (int k = 0; k < TOPK; k++) s += sc[ids[k]];
        float inv = 2.5f / s;
        for (int k = 0; k < TOPK; k++) {
            topk_ids[t * TOPK + k] = ids[k];
            topk_w[t * TOPK + k]   = sc[ids[k]] * inv;
        }
    }
}

// ---------------------------------------------------------------------------
// Counting sort into 128-aligned per-expert segments + tile table.
// Parallel: LDS atomics count, tid0 prefix-sums 16 segs, atomics scatter.
// Order within a segment is arbitrary - downstream math is order-invariant
// (per-slot rank-1 contributions summed by atomicAdd).
// ---------------------------------------------------------------------------
__global__ __launch_bounds__(256)
void build_map_kernel(const int* __restrict__ topk_ids, const float* __restrict__ topk_w,
                      int* __restrict__ map_token, float* __restrict__ map_w,
                      int4* __restrict__ tile_info)
{
    const int tid = threadIdx.x;
    __shared__ int cnt[NEXP], cur[NEXP];

    if (tid < NEXP) cnt[tid] = 0;
    // zero the whole map (padded slots must have weight 0)
    for (int i = tid; i < MAXSLOTS; i += 256) { map_token[i] = 0; map_w[i] = 0.f; }
    __syncthreads();

    for (int s = tid; s < T_TOK * TOPK; s += 256)
        atomicAdd(&cnt[topk_ids[s]], 1);
    __syncthreads();

    if (tid == 0) {
        int off = 0, tt = 0;
        for (int e = 0; e < NEXP; e++) {
            cur[e] = off;
            int tiles = (cnt[e] + BM - 1) / BM;
            for (int i = 0; i < tiles; i++) {
                int rem = cnt[e] - i * BM;
                tile_info[tt++] = make_int4(e, off + i * BM, rem < BM ? rem : BM, 0);
            }
            off += tiles * BM;
        }
        for (; tt < MAXTILES; tt++) tile_info[tt] = make_int4(-1, 0, 0, 0);
    }
    __syncthreads();

    for (int s = tid; s < T_TOK * TOPK; s += 256) {
        const int e = topk_ids[s];
        const int o = atomicAdd(&cur[e], 1);
        map_token[o] = s >> 2;        // token id
        map_w[o]     = topk_w[s];
    }
}

// ---------------------------------------------------------------------------
// SiLU(g)*u (* per-slot combine weight for the routed path).
// gu rows are [g | u] of width 2*I; grid covers rows*I/8 exactly.
// ---------------------------------------------------------------------------
__global__ void silu_kernel(const bf16_t* __restrict__ gu, bf16_t* __restrict__ act,
                            const float* __restrict__ w, int I)
{
    const unsigned idx = ((unsigned)blockIdx.x * blockDim.x + threadIdx.x) * 8u;
    const unsigned r = idx / (unsigned)I;
    const unsigned c = idx % (unsigned)I;
    const bf16x8 g = *(const bf16x8*)(gu + (size_t)r * 2 * I + c);
    const bf16x8 u = *(const bf16x8*)(gu + (size_t)r * 2 * I + I + c);
    const float wt = w ? w[r] : 1.0f;
    bf16x8 o;
#pragma unroll
    for (int j = 0; j < 8; j++) {
        float gf = (float)g[j], uf = (float)u[j];
        float a = gf / (1.f + expf(-gf)) * uf * wt;
        o[j] = (bf16_t)a;
    }
    *(bf16x8*)(act + (size_t)r * I + c) = o;
}

// ---------------------------------------------------------------------------
// Tiled bf16 MFMA GEMM, 128x128x32, 256 threads (4 waves, 2x2 of 64x64).
// A: bf16 [rows x lda] (optionally gathered rows via map_token).
// B: fp32 [K x N] row-major, converted to bf16 during LDS staging
//    (stored transposed [n][k] so fragments are contiguous 16B ds_read_b128).
// MODE 0: routed gate_up  (A rows = x[map_token[slot]],    C -> bf16 gu[slot])
// MODE 1: shared gate_up  (A rows = x[row],                C -> bf16 gu[row])
// MODE 2: routed down     (A rows = act[slot],  C -> atomicAdd f32 out[token])
// MODE 3: shared down     (A rows = act_s[row], C -> store f32 out[row])
// ---------------------------------------------------------------------------
template<int MODE>
__global__ __launch_bounds__(256, 2)
void gemm_kernel(const bf16_t* __restrict__ A, int lda,
                 const float* __restrict__ B, size_t bstride,
                 int K, int N,
                 const int4* __restrict__ tile_info,
                 const int* __restrict__ map_token,
                 bf16_t* __restrict__ Cb, float* __restrict__ Cf)
{
    const int tid = threadIdx.x;
    int row0, nvalid;
    const float* Bex;
    if (MODE == 0 || MODE == 2) {
        int4 ti = tile_info[blockIdx.y];
        if (ti.x < 0) return;                 // unused padded tile
        Bex = B + (size_t)ti.x * bstride;
        row0 = ti.y;
        nvalid = ti.z;
    } else {
        Bex = B;
        row0 = blockIdx.y * BM;
        nvalid = BM;
    }
    const int n0 = blockIdx.x * BN;

    __shared__ __align__(16) bf16_t As[BM * LDSS];
    __shared__ __align__(16) bf16_t Bs[BN * LDSS];

    // A staging: 512 chunks of 8 bf16 (16B); thread does rows r0 and r0+64
    const int r0 = tid >> 2;
    const int r1 = r0 + 64;
    const int kq = (tid & 3) * 8;
    const bool v0 = r0 < nvalid, v1 = r1 < nvalid;
    size_t arow0, arow1;
    if (MODE == 0) {
        arow0 = v0 ? (size_t)map_token[row0 + r0] : 0;
        arow1 = v1 ? (size_t)map_token[row0 + r1] : 0;
    } else {
        arow0 = (size_t)(row0 + r0);
        arow1 = (size_t)(row0 + r1);
    }
    // B staging: thread covers 16 k's at one n (k-strided coalesced dword loads)
    const int bn = tid & 127;
    const int bk = (tid >> 7) * 16;

    const int lane = tid & 63;
    const int wv = tid >> 6;
    const int wrow = (wv >> 1) * 64;
    const int wcol = (wv & 1) * 64;
    const int lr = lane & 15;
    const int lk = (lane >> 4) * 8;

    f32x4 acc[4][4];
    const f32x4 zero = {0.f, 0.f, 0.f, 0.f};
#pragma unroll
    for (int i = 0; i < 4; i++)
#pragma unroll
        for (int j = 0; j < 4; j++) acc[i][j] = zero;

    for (int k0 = 0; k0 < K; k0 += BK) {
        // ---- stage A (zero-fill rows past nvalid -> padded gu rows are 0) ----
        int4 a0 = make_int4(0, 0, 0, 0), a1 = make_int4(0, 0, 0, 0);
        if (v0) a0 = *(const int4*)(A + arow0 * lda + k0 + kq);
        if (v1) a1 = *(const int4*)(A + arow1 * lda + k0 + kq);
        *(int4*)(&As[r0 * LDSS + kq]) = a0;
        *(int4*)(&As[r1 * LDSS + kq]) = a1;
        // ---- stage B: fp32 -> bf16, transposed to [n][k] ----
        const float* bp = Bex + (size_t)(k0 + bk) * N + (n0 + bn);
        float bv[16];
#pragma unroll
        for (int i = 0; i < 16; i++) bv[i] = bp[(size_t)i * N];
        bf16x8 p0, p1;
#pragma unroll
        for (int i = 0; i < 8; i++) { p0[i] = (bf16_t)bv[i]; p1[i] = (bf16_t)bv[i + 8]; }
        *(bf16x8*)(&Bs[bn * LDSS + bk]) = p0;
        *(bf16x8*)(&Bs[bn * LDSS + bk + 8]) = p1;
        __syncthreads();
        // ---- fragments + MFMA ----
        bf16x8 af[4], bfrag[4];
#pragma unroll
        for (int im = 0; im < 4; im++)
            af[im] = *(const bf16x8*)(&As[(wrow + im * 16 + lr) * LDSS + lk]);
#pragma unroll
        for (int in = 0; in < 4; in++)
            bfrag[in] = *(const bf16x8*)(&Bs[(wcol + in * 16 + lr) * LDSS + lk]);
#pragma unroll
        for (int im = 0; im < 4; im++)
#pragma unroll
            for (int in = 0; in < 4; in++)
                acc[im][in] = __builtin_amdgcn_mfma_f32_16x16x32_bf16(
                    af[im], bfrag[in], acc[im][in], 0, 0, 0);
        __syncthreads();
    }

    // ---- epilogue: C/D layout col = lane&15, row = (lane>>4)*4 + reg ----
#pragma unroll
    for (int im = 0; im < 4; im++) {
#pragma unroll
        for (int j = 0; j < 4; j++) {
            const int rl = wrow + im * 16 + (lane >> 4) * 4 + j;
            if (MODE == 2) {
                if (rl < nvalid) {
                    const size_t orow = (size_t)map_token[row0 + rl] * N;
#pragma unroll
                    for (int in = 0; in < 4; in++) {
                        const int cl = n0 + wcol + in * 16 + (lane & 15);
                        atomicAdd(&Cf[orow + cl], acc[im][in][j]);
                    }
                }
            } else if (MODE == 3) {
                const size_t orow = (size_t)(row0 + rl) * N;
#pragma unroll
                for (int in = 0; in < 4; in++) {
                    const int cl = n0 + wcol + in * 16 + (lane & 15);
                    Cf[orow + cl] = acc[im][in][j];
                }
            } else {
                const size_t orow = (size_t)(row0 + rl) * N;
#pragma unroll
                for (int in = 0; in < 4; in++) {
                    const int cl = n0 + wcol + in * 16 + (lane & 15);
                    Cb[orow + cl] = (bf16_t)acc[im][in][j];
                }
            }
        }
    }
}

// ---------------------------------------------------------------------------
// Workspace layout (needs ~61 MB):
//   0x0000000  x_bf16      1024*2048*2   = 4 MB
//   0x0400000  topk_ids    4096*4
//   0x0404000  topk_w      4096*4
//   0x0408000  map_token   6144*4
//   0x0410000  map_w       6144*4
//   0x0418000  tile_info   48*16
//   0x0500000  act_routed  6144*1408*2   = 16.5 MB
//   0x1600000  act_shared  1024*2816*2   = 5.5 MB
//   0x1C00000  gu          6144*2816*2   = 33 MB   (reused by shared gate_up)
// ---------------------------------------------------------------------------
extern "C" void kernel_launch(void* const* d_in, const int* in_sizes, int n_in,
                              void* d_out, int out_size, void* d_ws, size_t ws_size,
                              hipStream_t stream)
{
    const float* x    = (const float*)d_in[0];
    const float* gw   = (const float*)d_in[1];
    const float* bias = (const float*)d_in[2];
    const float* wgu  = (const float*)d_in[3];
    const float* wdn  = (const float*)d_in[4];
    const float* sgu  = (const float*)d_in[5];
    const float* sdn  = (const float*)d_in[6];
    float* out = (float*)d_out;

    char* ws = (char*)d_ws;
    bf16_t* x_bf  = (bf16_t*)(ws);
    int*    tids  = (int*)  (ws + 0x400000);
    float*  tw    = (float*)(ws + 0x404000);
    int*    mtok  = (int*)  (ws + 0x408000);
    float*  mw    = (float*)(ws + 0x410000);
    int4*   tinfo = (int4*) (ws + 0x418000);
    bf16_t* act_r = (bf16_t*)(ws + 0x500000);
    bf16_t* act_s = (bf16_t*)(ws + 0x1600000);
    bf16_t* gu    = (bf16_t*)(ws + 0x1C00000);

    cvt_x_kernel<<<1024, 256, 0, stream>>>(x, x_bf);                 // 1024*256*8 == T*H
    router_kernel<<<T_TOK, 64, 0, stream>>>(x, gw, bias, tids, tw);
    build_map_kernel<<<1, 256, 0, stream>>>(tids, tw, mtok, mw, tinfo);

    // routed gate_up: [slots x 2816] = gather(x) @ w_gate_up[e]
    gemm_kernel<0><<<dim3(2 * IDIM / BN, MAXTILES), 256, 0, stream>>>(
        x_bf, HDIM, wgu, (size_t)HDIM * 2 * IDIM, HDIM, 2 * IDIM, tinfo, mtok, gu, nullptr);
    // silu + combine weight -> act_r
    silu_kernel<<<MAXSLOTS * IDIM / (8 * 256), 256, 0, stream>>>(gu, act_r, mw, IDIM);

    // shared gate_up (reuses gu buffer)
    gemm_kernel<1><<<dim3(2 * ISH / BN, T_TOK / BM), 256, 0, stream>>>(
        x_bf, HDIM, sgu, 0, HDIM, 2 * ISH, nullptr, nullptr, gu, nullptr);
    silu_kernel<<<T_TOK * ISH / (8 * 256), 256, 0, stream>>>(gu, act_s, nullptr, ISH);

    // shared down: writes every element of d_out (initializes it)
    gemm_kernel<3><<<dim3(HDIM / BN, T_TOK / BM), 256, 0, stream>>>(
        act_s, ISH, sdn, 0, ISH, HDIM, nullptr, nullptr, nullptr, out);
    // routed down: atomicAdd per-token contributions on top
    gemm_kernel<2><<<dim3(HDIM / BN, MAXTILES), 256, 0, stream>>>(
        act_r, IDIM, wdn, (size_t)IDIM * HDIM, IDIM, HDIM, tinfo, mtok, nullptr, out);
}